// Round 2
// baseline (635.104 us; speedup 1.0000x reference)
//
#include <hip/hip_runtime.h>
#include <hip/hip_bf16.h>
#include <math.h>

// Problem constants (B=2, T=1024, C=1024, nh=16, hs=64, bd=16, delta=64)
#define TB   2
#define TT   1024
#define TC   1024
#define NH   16
#define HS   64
#define BDI  16
#define DLT  64

// ---------------------------------------------------------------------------
// Classic LDS-tiled GEMM: C[M,N] = A[M,K] * B[K,N], all f32.
// BM=BN=64, BK=16, 256 threads, 4x4 outputs/thread. Correctness-first; MFMA
// (with in-kernel bf16 cast) planned for later rounds.
// ---------------------------------------------------------------------------
__global__ __launch_bounds__(256) void gemm_k(const float* __restrict__ A,
                                              const float* __restrict__ Bm,
                                              float* __restrict__ C,
                                              int M, int N, int K) {
    const int BM = 64, BN = 64, BK = 16;
    __shared__ float As[BK][BM + 1];
    __shared__ float Bs[BK][BN + 1];
    const int tid = threadIdx.x;
    const int tx = tid & 15;        // 0..15 -> N micro
    const int ty = tid >> 4;        // 0..15 -> M micro
    const int row0 = blockIdx.y * BM;
    const int col0 = blockIdx.x * BN;

    float acc[4][4] = {};

    for (int k0 = 0; k0 < K; k0 += BK) {
        // A tile: BM x BK (1024 elems, 4/thread, consecutive k per thread)
#pragma unroll
        for (int i = 0; i < 4; i++) {
            int idx = tid * 4 + i;          // 0..1023
            int m = idx >> 4;               // /BK
            int kk = idx & 15;              // %BK
            As[kk][m] = A[(long long)(row0 + m) * K + k0 + kk];
        }
        // B tile: BK x BN (1024 elems, 4/thread, consecutive n per thread)
#pragma unroll
        for (int i = 0; i < 4; i++) {
            int idx = tid * 4 + i;
            int kk = idx >> 6;              // /BN
            int n = idx & 63;               // %BN
            Bs[kk][n] = Bm[(long long)(k0 + kk) * N + col0 + n];
        }
        __syncthreads();
#pragma unroll
        for (int kk = 0; kk < BK; kk++) {
            float a[4], b[4];
#pragma unroll
            for (int i = 0; i < 4; i++) a[i] = As[kk][ty * 4 + i];
#pragma unroll
            for (int j = 0; j < 4; j++) b[j] = Bs[kk][tx * 4 + j];
#pragma unroll
            for (int i = 0; i < 4; i++)
#pragma unroll
                for (int j = 0; j < 4; j++) acc[i][j] += a[i] * b[j];
        }
        __syncthreads();
    }
#pragma unroll
    for (int i = 0; i < 4; i++)
#pragma unroll
        for (int j = 0; j < 4; j++)
            C[(long long)(row0 + ty * 4 + i) * N + col0 + tx * 4 + j] = acc[i][j];
}

// ---------------------------------------------------------------------------
// Windowed peridynamic attention. One 64-lane wave per (b, h, t); lane j owns
// window slot j (t' = t-63+j). 4 waves / 256-thread block.
// disp: (B*T, nh*bd) f32   val: (B*T, nh*hs) f32   attnout: (B*T, nh*hs) f32
// ---------------------------------------------------------------------------
__global__ __launch_bounds__(256) void attn_k(
    const float* __restrict__ disp, const float* __restrict__ val,
    const float* __restrict__ rel_pos_emb,   // (64,16)
    const float* __restrict__ W_strain,      // (16,16)
    const float* __restrict__ W_pos,         // (16,16)
    const float* __restrict__ W_bond,        // (16,1)
    const float* __restrict__ W_dmg,         // (16,16)
    const float* __restrict__ b_dmg,         // (16,)
    const float* __restrict__ W_dmg_out,     // (16,1)
    const float* __restrict__ b_dmg_out,     // (1,)
    float* __restrict__ attnout) {
    __shared__ float sWs[BDI][BDI];   // W_strain[k][d]
    __shared__ float sWd[BDI][BDI];   // W_dmg[k][d]
    __shared__ float sPe[DLT][BDI];   // rel_emb @ W_pos  (per-slot bias)
    __shared__ float sWb[BDI], sbd[BDI], sWdo[BDI];
    __shared__ float sbo;

    const int tid = threadIdx.x;
    {
        int d = tid & 15, k = tid >> 4;   // tid in [0,256): k,d in [0,16)
        sWs[k][d] = W_strain[k * BDI + d];
        sWd[k][d] = W_dmg[k * BDI + d];
    }
    if (tid < BDI) {
        sWb[tid] = W_bond[tid];
        sbd[tid] = b_dmg[tid];
        sWdo[tid] = W_dmg_out[tid];
    }
    if (tid == 0) sbo = b_dmg_out[0];
#pragma unroll
    for (int i = 0; i < 4; i++) {           // 64*16 = 1024 entries, 4/thread
        int idx = tid * 4 + i;
        int j = idx >> 4, d = idx & 15;
        float s = 0.f;
#pragma unroll
        for (int k = 0; k < BDI; k++)
            s += rel_pos_emb[j * BDI + k] * W_pos[k * BDI + d];
        sPe[j][d] = s;
    }
    __syncthreads();

    const int wave = tid >> 6;
    const int lane = tid & 63;
    const int w = blockIdx.x * 4 + wave;        // [0, B*nh*T)
    const int t = w & (TT - 1);
    const int bh = w >> 10;                     // /T
    const int h = bh & (NH - 1);
    const int b = bh >> 4;

    const float* dispT = disp + ((long long)(b * TT + t) * (NH * BDI) + h * BDI);
    float dt[BDI];
#pragma unroll
    for (int d = 0; d < BDI; d++) dt[d] = dispT[d];

    const int j = lane;
    const int tp = t - (DLT - 1) + j;
    const bool valid = tp >= 0;

    float strain[BDI];
    if (valid) {
        const float* dispP = disp + ((long long)(b * TT + tp) * (NH * BDI) + h * BDI);
#pragma unroll
        for (int d = 0; d < BDI; d++) strain[d] = dispP[d] - dt[d];
    } else {
#pragma unroll
        for (int d = 0; d < BDI; d++) strain[d] = 0.f;
    }

    float bond = 0.f, dmg = 0.f;
#pragma unroll
    for (int d2 = 0; d2 < BDI; d2++) {
        float sa = sPe[j][d2];
        float da = sbd[d2];
#pragma unroll
        for (int d = 0; d < BDI; d++) {
            sa += strain[d] * sWs[d][d2];
            da += strain[d] * sWd[d][d2];
        }
        const float inv_sqrt2 = 0.70710678118654752f;
        float ga = 0.5f * sa * (1.f + erff(sa * inv_sqrt2));   // exact gelu
        float gd = 0.5f * da * (1.f + erff(da * inv_sqrt2));
        bond += ga * sWb[d2];
        dmg += gd * sWdo[d2];
    }
    float damage = 1.f / (1.f + expf(-(dmg + sbo)));
    float logit = valid ? (bond - 10.f * damage) : -__builtin_inff();

    // wave-wide softmax over the 64 window slots
    float m = logit;
#pragma unroll
    for (int off = 32; off >= 1; off >>= 1) m = fmaxf(m, __shfl_xor(m, off));
    float e = valid ? expf(logit - m) : 0.f;
    float s = e;
#pragma unroll
    for (int off = 32; off >= 1; off >>= 1) s += __shfl_xor(s, off);
    float wgt = e / s;

    // PV: lane = output channel e in [0,64); broadcast weights per slot
    float acc = 0.f;
    const int j2start = (t >= DLT - 1) ? 0 : (DLT - 1 - t);
    for (int j2 = j2start; j2 < DLT; j2++) {
        float wj = __shfl(wgt, j2);
        int tpp = t - (DLT - 1) + j2;
        acc += wj * val[(long long)(b * TT + tpp) * (NH * HS) + h * HS + lane];
    }
    attnout[(long long)(b * TT + t) * (NH * HS) + h * HS + lane] = acc;
}

extern "C" void kernel_launch(void* const* d_in, const int* in_sizes, int n_in,
                              void* d_out, int out_size, void* d_ws, size_t ws_size,
                              hipStream_t stream) {
    const float* x      = (const float*)d_in[0];
    const float* W_disp = (const float*)d_in[1];
    const float* W_val  = (const float*)d_in[2];
    const float* rel    = (const float*)d_in[3];
    const float* Ws     = (const float*)d_in[4];
    const float* Wp     = (const float*)d_in[5];
    const float* Wb     = (const float*)d_in[6];
    const float* Wd     = (const float*)d_in[7];
    const float* bd_    = (const float*)d_in[8];
    const float* Wdo    = (const float*)d_in[9];
    const float* bdo    = (const float*)d_in[10];
    const float* Wc     = (const float*)d_in[11];
    float* out = (float*)d_out;

    const int M = TB * TT;                       // 2048
    float* disp = (float*)d_ws;                  // M * 256
    float* val  = disp + (size_t)M * (NH * BDI); // M * 1024
    float* attn = val  + (size_t)M * TC;         // M * 1024

    dim3 blk(256);
    // disp = x @ W_disp   (2048 x 256, K=1024)
    gemm_k<<<dim3((NH * BDI) / 64, M / 64), blk, 0, stream>>>(x, W_disp, disp, M, NH * BDI, TC);
    // val = x @ W_val     (2048 x 1024, K=1024)
    gemm_k<<<dim3(TC / 64, M / 64), blk, 0, stream>>>(x, W_val, val, M, TC, TC);
    // windowed attention  (one wave per (b,h,t))
    attn_k<<<(TB * NH * TT) / 4, blk, 0, stream>>>(disp, val, rel, Ws, Wp, Wb, Wd,
                                                   bd_, Wdo, bdo, attn);
    // out = attn @ W_cproj (2048 x 1024, K=1024)
    gemm_k<<<dim3(TC / 64, M / 64), blk, 0, stream>>>(attn, Wc, out, M, TC, TC);
}

// Round 3
// 265.905 us; speedup vs baseline: 2.3885x; 2.3885x over previous
//
#include <hip/hip_runtime.h>
#include <hip/hip_bf16.h>
#include <math.h>

// Problem constants (B=2, T=1024, C=1024, nh=16, hs=64, bd=16, delta=64)
#define TB   2
#define TT   1024
#define TC   1024
#define NH   16
#define HS   64
#define BDI  16
#define DLT  64
#define LDD  1280   // fused disp|val row stride (256 + 1024)

typedef __attribute__((ext_vector_type(8))) short short8;
typedef __attribute__((ext_vector_type(4))) float floatx4;
typedef __hip_bfloat16 bf16;

// ---------------------------------------------------------------------------
// async global->LDS, 16B per lane. LDS dest = wave-uniform base + lane*16.
// ---------------------------------------------------------------------------
__device__ __forceinline__ void gload_lds16(const void* g, void* l) {
    __builtin_amdgcn_global_load_lds(
        (const __attribute__((address_space(1))) unsigned int*)(unsigned long long)g,
        (__attribute__((address_space(3))) unsigned int*)(unsigned int)(unsigned long long)l,
        16, 0, 0);
}

// ---------------------------------------------------------------------------
// f32 -> bf16 cast, 4 elems/thread
// ---------------------------------------------------------------------------
__global__ __launch_bounds__(256) void cast_bf16_k(const float* __restrict__ in,
                                                   bf16* __restrict__ out, int n) {
    int i = (blockIdx.x * 256 + threadIdx.x) * 4;
    if (i >= n) return;
    float4 v = *(const float4*)(in + i);
    bf16 o0 = __float2bfloat16(v.x), o1 = __float2bfloat16(v.y);
    bf16 o2 = __float2bfloat16(v.z), o3 = __float2bfloat16(v.w);
    ushort4 u;
    u.x = *(unsigned short*)&o0; u.y = *(unsigned short*)&o1;
    u.z = *(unsigned short*)&o2; u.w = *(unsigned short*)&o3;
    *(ushort4*)(out + i) = u;
}

// ---------------------------------------------------------------------------
// transpose + cast: in (K,N) f32 row-major -> out (N,K) bf16 row-major
// block 256 = 32x8, 32x32 LDS tile (+1 pad)
// ---------------------------------------------------------------------------
__global__ __launch_bounds__(256) void tpose_cast_k(const float* __restrict__ in,
                                                    bf16* __restrict__ outp,
                                                    int K, int N) {
    __shared__ float tile[32][33];
    const int tx = threadIdx.x & 31, ty4 = (threadIdx.x >> 5) * 4;
    const int k0 = blockIdx.x * 32, n0 = blockIdx.y * 32;
#pragma unroll
    for (int i = 0; i < 4; i++)
        tile[ty4 + i][tx] = in[(long long)(k0 + ty4 + i) * N + n0 + tx];
    __syncthreads();
#pragma unroll
    for (int i = 0; i < 4; i++)
        outp[(long long)(n0 + ty4 + i) * K + k0 + tx] = __float2bfloat16(tile[tx][ty4 + i]);
}

// ---------------------------------------------------------------------------
// MFMA bf16 GEMM: C[M,N] f32 = A[M,K] bf16 * Bt[N,K] bf16 (B transposed).
// 128x128 tile, BK=32, 256 threads = 4 waves (2x2 of 64x64), 16x16x32 MFMA.
// global_load_lds width-16 staging (m97 structure).
// ---------------------------------------------------------------------------
__global__ __launch_bounds__(256) void mfma_gemm_k(const bf16* __restrict__ A,
                                                   const bf16* __restrict__ Bt,
                                                   float* __restrict__ C,
                                                   int M, int N, int K) {
    __shared__ __align__(16) bf16 As[128 * 32];
    __shared__ __align__(16) bf16 Bs[128 * 32];
    const int tid = threadIdx.x;
    const int w = tid >> 6, lane = tid & 63;
    const int row0 = blockIdx.y * 128, col0 = blockIdx.x * 128;
    const int wm = (w >> 1) * 64, wn = (w & 1) * 64;

    // staging: tile = 8192B = 8 chunks of 1024B (64 lanes x 16B). wave w owns
    // chunks w and w+4. chunk c covers 16B-units [c*64, c*64+64); unit u ->
    // row = u>>2 (64B rows), kchunk = u&3 (8 bf16).
    const int f0 = w * 64 + lane, f1 = (w + 4) * 64 + lane;
    const bf16* gA0 = A + (long long)(row0 + (f0 >> 2)) * K + (f0 & 3) * 8;
    const bf16* gA1 = A + (long long)(row0 + (f1 >> 2)) * K + (f1 & 3) * 8;
    const bf16* gB0 = Bt + (long long)(col0 + (f0 >> 2)) * K + (f0 & 3) * 8;
    const bf16* gB1 = Bt + (long long)(col0 + (f1 >> 2)) * K + (f1 & 3) * 8;
    bf16* lA0 = &As[w * 512];       bf16* lA1 = &As[(w + 4) * 512];
    bf16* lB0 = &Bs[w * 512];       bf16* lB1 = &Bs[(w + 4) * 512];

    floatx4 acc[4][4] = {};
    const int kq = (lane >> 4) * 8;   // k-offset of this lane's 8 elements
    const int rA = lane & 15;         // row within 16-tile

    for (int k0 = 0; k0 < K; k0 += 32) {
        gload_lds16(gA0, lA0); gload_lds16(gA1, lA1);
        gload_lds16(gB0, lB0); gload_lds16(gB1, lB1);
        gA0 += 32; gA1 += 32; gB0 += 32; gB1 += 32;
        __syncthreads();                       // drains vmcnt -> LDS visible
        short8 af[4], bfr[4];
#pragma unroll
        for (int i = 0; i < 4; i++) {
            af[i]  = *(const short8*)&As[(wm + i * 16 + rA) * 32 + kq];
            bfr[i] = *(const short8*)&Bs[(wn + i * 16 + rA) * 32 + kq];
        }
#pragma unroll
        for (int i = 0; i < 4; i++)
#pragma unroll
            for (int j = 0; j < 4; j++)
                acc[i][j] = __builtin_amdgcn_mfma_f32_16x16x32_bf16(af[i], bfr[j], acc[i][j], 0, 0, 0);
        __syncthreads();
    }
    // C/D layout: col = lane&15, row = (lane>>4)*4 + reg   [m89/m91 verified]
    const int cn = lane & 15, rq = (lane >> 4) * 4;
#pragma unroll
    for (int i = 0; i < 4; i++)
#pragma unroll
        for (int j = 0; j < 4; j++) {
            long long base = (long long)(row0 + wm + i * 16 + rq) * N + col0 + wn + j * 16 + cn;
#pragma unroll
            for (int r = 0; r < 4; r++)
                C[base + (long long)r * N] = acc[i][j][r];
        }
}

// ---------------------------------------------------------------------------
// Windowed peridynamic attention. One wave per (b,h,t); lane j = window slot.
// dv: (B*T, 1280) f32 = [disp(256) | val(1024)].  Output bf16 (feeds cproj).
// ---------------------------------------------------------------------------
__global__ __launch_bounds__(256) void attn_k(
    const float* __restrict__ dv,
    const float* __restrict__ rel_pos_emb,   // (64,16)
    const float* __restrict__ W_strain,      // (16,16)
    const float* __restrict__ W_pos,         // (16,16)
    const float* __restrict__ W_bond,        // (16,1)
    const float* __restrict__ W_dmg,         // (16,16)
    const float* __restrict__ b_dmg,         // (16,)
    const float* __restrict__ W_dmg_out,     // (16,1)
    const float* __restrict__ b_dmg_out,     // (1,)
    bf16* __restrict__ attnout) {
    __shared__ float sWs[BDI][BDI];       // W_strain[k][d]
    __shared__ float sWd[BDI][BDI];       // W_dmg[k][d]
    __shared__ float sPe[DLT][BDI + 1];   // rel_emb @ W_pos, +1 pad: stride 17 -> 2-way (free)
    __shared__ float sWb[BDI], sbd[BDI], sWdo[BDI];
    __shared__ float sbo;

    const int tid = threadIdx.x;
    {
        int d = tid & 15, k = tid >> 4;
        sWs[k][d] = W_strain[k * BDI + d];
        sWd[k][d] = W_dmg[k * BDI + d];
    }
    if (tid < BDI) {
        sWb[tid] = W_bond[tid];
        sbd[tid] = b_dmg[tid];
        sWdo[tid] = W_dmg_out[tid];
    }
    if (tid == 0) sbo = b_dmg_out[0];
#pragma unroll
    for (int i = 0; i < 4; i++) {            // 64*16 entries, 4/thread
        int idx = tid * 4 + i;
        int j = idx >> 4, d = idx & 15;
        float s = 0.f;
#pragma unroll
        for (int k = 0; k < BDI; k++)
            s += rel_pos_emb[j * BDI + k] * W_pos[k * BDI + d];
        sPe[j][d] = s;
    }
    __syncthreads();

    const int wave = tid >> 6;
    const int lane = tid & 63;
    const int w = blockIdx.x * 4 + wave;        // [0, B*nh*T)
    const int t = w & (TT - 1);
    const int bh = w >> 10;
    const int h = bh & (NH - 1);
    const int b = bh >> 4;

    const float* dispT = dv + ((long long)(b * TT + t) * LDD + h * BDI);
    float4 dt0 = *(const float4*)(dispT + 0);
    float4 dt1 = *(const float4*)(dispT + 4);
    float4 dt2 = *(const float4*)(dispT + 8);
    float4 dt3 = *(const float4*)(dispT + 12);
    float dt[BDI] = {dt0.x, dt0.y, dt0.z, dt0.w, dt1.x, dt1.y, dt1.z, dt1.w,
                     dt2.x, dt2.y, dt2.z, dt2.w, dt3.x, dt3.y, dt3.z, dt3.w};

    const int j = lane;
    const int tp = t - (DLT - 1) + j;
    const bool valid = tp >= 0;

    float strain[BDI];
    {
        const int tpc = valid ? tp : 0;
        const float* dispP = dv + ((long long)(b * TT + tpc) * LDD + h * BDI);
        float4 p0 = *(const float4*)(dispP + 0);
        float4 p1 = *(const float4*)(dispP + 4);
        float4 p2 = *(const float4*)(dispP + 8);
        float4 p3 = *(const float4*)(dispP + 12);
        float pp[BDI] = {p0.x, p0.y, p0.z, p0.w, p1.x, p1.y, p1.z, p1.w,
                         p2.x, p2.y, p2.z, p2.w, p3.x, p3.y, p3.z, p3.w};
#pragma unroll
        for (int d = 0; d < BDI; d++) strain[d] = valid ? (pp[d] - dt[d]) : 0.f;
    }

    float bond = 0.f, dmg = 0.f;
#pragma unroll
    for (int d2 = 0; d2 < BDI; d2++) {
        float sa = sPe[j][d2];
        float da = sbd[d2];
#pragma unroll
        for (int d = 0; d < BDI; d++) {
            sa += strain[d] * sWs[d][d2];
            da += strain[d] * sWd[d][d2];
        }
        const float inv_sqrt2 = 0.70710678118654752f;
        float ga = 0.5f * sa * (1.f + erff(sa * inv_sqrt2));   // exact gelu
        float gd = 0.5f * da * (1.f + erff(da * inv_sqrt2));
        bond += ga * sWb[d2];
        dmg += gd * sWdo[d2];
    }
    float damage = 1.f / (1.f + expf(-(dmg + sbo)));
    float logit = valid ? (bond - 10.f * damage) : -__builtin_inff();

    // wave-wide softmax over 64 slots
    float m = logit;
#pragma unroll
    for (int off = 32; off >= 1; off >>= 1) m = fmaxf(m, __shfl_xor(m, off));
    float e = valid ? expf(logit - m) : 0.f;
    float s = e;
#pragma unroll
    for (int off = 32; off >= 1; off >>= 1) s += __shfl_xor(s, off);
    float wgt = e / s;

    // PV: lane = output channel; fixed-trip fully-unrollable loop, clamped row
    // (invalid slots carry wgt==0 so the clamped read contributes nothing)
    const float* vbase = dv + (long long)(b * TT) * LDD + 256 + h * HS + lane;
    float acc = 0.f;
#pragma unroll
    for (int j2 = 0; j2 < DLT; j2++) {
        float wj = __shfl(wgt, j2);
        int tpp = t - (DLT - 1) + j2;
        tpp = tpp < 0 ? 0 : tpp;
        acc += wj * vbase[(long long)tpp * LDD];
    }
    attnout[(long long)(b * TT + t) * TC + h * HS + lane] = __float2bfloat16(acc);
}

extern "C" void kernel_launch(void* const* d_in, const int* in_sizes, int n_in,
                              void* d_out, int out_size, void* d_ws, size_t ws_size,
                              hipStream_t stream) {
    const float* x      = (const float*)d_in[0];
    const float* W_disp = (const float*)d_in[1];
    const float* W_val  = (const float*)d_in[2];
    const float* rel    = (const float*)d_in[3];
    const float* Ws     = (const float*)d_in[4];
    const float* Wp     = (const float*)d_in[5];
    const float* Wb     = (const float*)d_in[6];
    const float* Wd     = (const float*)d_in[7];
    const float* bd_    = (const float*)d_in[8];
    const float* Wdo    = (const float*)d_in[9];
    const float* bdo    = (const float*)d_in[10];
    const float* Wc     = (const float*)d_in[11];
    float* out = (float*)d_out;

    const int M = TB * TT;   // 2048
    char* ws = (char*)d_ws;
    // [0, 4MB):        xb (2048x1024 bf16); reused later as attnb
    // [4MB, 6.625MB):  Wdvt (1280x1024 bf16); reused later as Wct (1024x1024)
    // [6.625MB, ...):  dvC (2048x1280 f32) = [disp|val]
    bf16*  xb    = (bf16*)ws;
    bf16*  attnb = (bf16*)ws;                                   // alias (xb dead)
    bf16*  Wdvt  = (bf16*)(ws + (size_t)4 * 1024 * 1024);
    bf16*  Wct   = (bf16*)(ws + (size_t)4 * 1024 * 1024);       // alias (Wdvt dead)
    float* dvC   = (float*)(ws + (size_t)4 * 1024 * 1024 + (size_t)2 * LDD * 1024);

    dim3 blk(256);
    // 1. cast x -> bf16
    cast_bf16_k<<<(M * TC / 4 + 255) / 256, blk, 0, stream>>>(x, xb, M * TC);
    // 2+3. transpose-cast W_disp (1024x256) and W_val (1024x1024) into Wdvt (1280x1024)
    tpose_cast_k<<<dim3(TC / 32, 256 / 32), blk, 0, stream>>>(W_disp, Wdvt, TC, 256);
    tpose_cast_k<<<dim3(TC / 32, TC / 32), blk, 0, stream>>>(W_val, Wdvt + (size_t)256 * TC, TC, TC);
    // 4. fused disp|val projection: (2048x1280) = xb (2048x1024) * Wdvt^T
    mfma_gemm_k<<<dim3(LDD / 128, M / 128), blk, 0, stream>>>(xb, Wdvt, dvC, M, LDD, TC);
    // 5. windowed attention -> bf16 (overwrites xb region)
    attn_k<<<(TB * NH * TT) / 4, blk, 0, stream>>>(dvC, rel, Ws, Wp, Wb, Wd,
                                                   bd_, Wdo, bdo, attnb);
    // 6. transpose-cast W_cproj (after GEMM4 released Wdvt)
    tpose_cast_k<<<dim3(TC / 32, TC / 32), blk, 0, stream>>>(Wc, Wct, TC, TC);
    // 7. out = attn @ W_cproj
    mfma_gemm_k<<<dim3(TC / 128, M / 128), blk, 0, stream>>>(attnb, Wct, out, M, TC, TC);
}